// Round 2
// baseline (1202.353 us; speedup 1.0000x reference)
//
#include <hip/hip_runtime.h>

#define CUT 32
#define TILE 256                 // rows per block
#define NF4 (TILE * 8)           // float4s per staged array (2048)

// W2[n][m] = (re, im) of kerr[m] * G[m][n], interleaved. 8 KiB.
__device__ __align__(16) float g_W2[CUT * CUT * 2];

// ---------------------------------------------------------------------------
// Kernel A: build the Gaussian-unitary matrix (with Kerr folded in) in fp64.
// One wave. Lane m (m < 32) owns row m of the current column.
// ---------------------------------------------------------------------------
__global__ __launch_bounds__(64) void build_W(
    const float* __restrict__ gre, const float* __restrict__ gim,
    const float* __restrict__ phi_p, const float* __restrict__ zre,
    const float* __restrict__ zim, const float* __restrict__ kap)
{
    const int lane = threadIdx.x;

    const double gr = (double)gre[0], gi = (double)gim[0];
    const double ph = (double)phi_p[0];
    const double zr = (double)zre[0], zi = (double)zim[0];
    const double kp = (double)kap[0];

    const double r     = sqrt(zr * zr + zi * zi);
    const double delta = atan2(zi, zr);
    const double T     = tanh(r);
    const double sech  = 1.0 / cosh(r);

    const double adp = delta + 2.0 * ph;
    const double edr = cos(adp), edi = sin(adp);   // e^{i(delta+2phi)}

    // g00 = exp(-0.5*(|g|^2 + conj(g)^2 * eidp * T)) * sqrt(sech)
    const double cg2r = gr * gr - gi * gi, cg2i = -2.0 * gr * gi;
    const double wr_  = (cg2r * edr - cg2i * edi) * T;
    const double wi_  = (cg2r * edi + cg2i * edr) * T;
    const double exr  = -0.5 * (gr * gr + gi * gi + wr_);
    const double exi  = -0.5 * wi_;
    const double mag  = exp(exr) * sqrt(sech);
    const double g00r = mag * cos(exi), g00i = mag * sin(exi);

    // A = gamma + conj(gamma)*eidp*T ; B = eidp*T
    const double cgTr = (gr * edr + gi * edi) * T;
    const double cgTi = (gr * edi - gi * edr) * T;
    const double Ar = gr + cgTr, Ai = gi + cgTi;
    const double Br = edr * T,   Bi = edi * T;

    // per-lane sqrt tables (extracted with __shfl during the serial loops)
    const double dl  = (double)lane;
    const double sq  = sqrt(dl);                       // sqrt(lane)
    const double isq = (lane > 0) ? 1.0 / sq : 0.0;    // 1/sqrt(lane)

    // ---- column 0: serial three-term recurrence in m (uniform values) ----
    double cr = (lane == 0) ? g00r : 0.0;
    double ci = (lane == 0) ? g00i : 0.0;
    double g1r = g00r, g1i = g00i, g2r = 0.0, g2i = 0.0;
    for (int m = 1; m < CUT; ++m) {
        const double sm1 = __shfl(sq, m - 1);
        const double ism = __shfl(isq, m);
        double tr = Ar * g1r - Ai * g1i - sm1 * (Br * g2r - Bi * g2i);
        double ti = Ar * g1i + Ai * g1r - sm1 * (Br * g2i + Bi * g2r);
        tr *= ism; ti *= ism;
        if (lane == m) { cr = tr; ci = ti; }
        g2r = g1r; g2i = g1i; g1r = tr; g1i = ti;
    }

    const double Pr = cos(ph) * sech,  Pi = sin(ph) * sech;   // e^{i phi} sech
    const double Qr = cos(delta) * T,  Qi = -sin(delta) * T;  // e^{-i delta} tanh
    const double gbr = gr, gbi = -gi;                         // conj(gamma)

    // Kerr factor for row m = lane: e^{i kappa m^2}
    const double ka = kp * dl * dl;
    const double kr = cos(ka), ki = sin(ka);

    if (lane < CUT) {
        g_W2[(0 * CUT + lane) * 2 + 0] = (float)(kr * cr - ki * ci);
        g_W2[(0 * CUT + lane) * 2 + 1] = (float)(kr * ci + ki * cr);
    }

    // ---- columns n -> n+1: parallel in m, shift via shfl_up ----
    double pr = 0.0, pi = 0.0;
    for (int n = 0; n < CUT - 1; ++n) {
        double upr = __shfl_up(cr, 1);
        double upi = __shfl_up(ci, 1);
        if (lane == 0) { upr = 0.0; upi = 0.0; }
        const double sn   = __shfl(sq, n);
        const double isn1 = __shfl(isq, n + 1);
        // t = sqrt(m)*c[m-1] - conj(gamma)*c[m]
        const double tr = sq * upr - (gbr * cr - gbi * ci);
        const double ti = sq * upi - (gbr * ci + gbi * cr);
        // u = (P*t + Q*sqrt(n)*c_prev) / sqrt(n+1)
        double ur = (Pr * tr - Pi * ti + sn * (Qr * pr - Qi * pi)) * isn1;
        double ui = (Pr * ti + Pi * tr + sn * (Qr * pi + Qi * pr)) * isn1;
        if (lane < CUT) {
            g_W2[((n + 1) * CUT + lane) * 2 + 0] = (float)(kr * ur - ki * ui);
            g_W2[((n + 1) * CUT + lane) * 2 + 1] = (float)(kr * ui + ki * ur);
        }
        pr = cr; pi = ci; cr = ur; ci = ui;
    }
}

// ---------------------------------------------------------------------------
// Kernel B: out[b,m] = sum_n W[m,n] * state[b,n].
// Block stages TILE=256 rows of sre/sim into LDS via global_load_lds with
// fully-coalesced (1 KB/wave-instruction) reads. LDS rows are XOR-swizzled
// (slot = chunk ^ (row&7)) via pre-swizzled SOURCE addresses (linear dest, as
// global_load_lds requires), so per-thread row reads are conflict-minimal
// 8-way ds_read_b128 instead of the 32-way conflict of linear 128 B rows.
// Output uses nontemporal stores to avoid L2 write-allocate fetches.
// ---------------------------------------------------------------------------
typedef __attribute__((address_space(3))) char* lds_cast_t;
typedef const __attribute__((address_space(1))) char* gbl_cast_t;
typedef float __attribute__((ext_vector_type(4))) f32x4;

__device__ __forceinline__ void gload_lds16(const void* g, void* l) {
    __builtin_amdgcn_global_load_lds((gbl_cast_t)g, (lds_cast_t)l, 16, 0, 0);
}

__global__ __launch_bounds__(256, 2) void apply_W(
    const float* __restrict__ sre, const float* __restrict__ sim,
    float* __restrict__ out, int batch)
{
    __shared__ __align__(16) float4 Lre[NF4];
    __shared__ __align__(16) float4 Lim[NF4];
    __shared__ __align__(16) float  W[CUT * CUT * 2];

    const int t  = threadIdx.x;
    const int wv = t >> 6;                       // wave id 0..3 (uniform/wave)
    const long row0 = (long)blockIdx.x * TILE;

    const float4* sre4 = (const float4*)sre;
    const float4* sim4 = (const float4*)sim;
    const float4* w4g  = (const float4*)g_W2;

    // ---- stage W (512 float4, linear, no swizzle: reads are broadcast) ----
    {
        float4* W4 = (float4*)W;
        #pragma unroll
        for (int i = 0; i < 2; ++i) {
            gload_lds16(w4g + (i * 256 + t), W4 + (i * 256 + wv * 64));
        }
    }

    // ---- stage state tile, pre-swizzled source / linear dest ----
    const long maxr = (long)batch - 1;
    #pragma unroll
    for (int i = 0; i < 8; ++i) {
        const int p   = i * 256 + t;     // local float4 index (dest)
        const int row = p >> 3;          // local row 0..255
        const int s   = p & 7;           // dest slot within row
        const int c   = s ^ (row & 7);   // source chunk feeding this slot
        long grow = row0 + row;
        if (grow > maxr) grow = maxr;    // tail clamp (stores are guarded)
        const long gidx = grow * 8 + c;
        const int  lbase = i * 256 + wv * 64;   // wave-uniform dest base
        gload_lds16(sre4 + gidx, Lre + lbase);
        gload_lds16(sim4 + gidx, Lim + lbase);
    }

    asm volatile("s_waitcnt vmcnt(0)" ::: "memory");
    __syncthreads();

    // ---- compute: one row per thread, 64 fp32 accumulators ----
    float ar[CUT], ai[CUT];
    #pragma unroll
    for (int m = 0; m < CUT; ++m) { ar[m] = 0.f; ai[m] = 0.f; }

    const float4* LreT = &Lre[t * 8];
    const float4* LimT = &Lim[t * 8];

    #pragma unroll
    for (int jj = 0; jj < 8; ++jj) {
        const int slot = jj ^ (t & 7);          // chunk jj lives at this slot
        const float4 re = LreT[slot];
        const float4 im = LimT[slot];

        #define DO_Q(q, SR, SI)                                               \
        {                                                                     \
            const float sr = SR, si = SI;                                     \
            const float* Wn = &W[(jj * 4 + q) * (2 * CUT)];                   \
            _Pragma("unroll")                                                 \
            for (int m2 = 0; m2 < 16; ++m2) {                                 \
                const float4 wvv = *(const float4*)&Wn[4 * m2];               \
                const int m = 2 * m2;                                         \
                ar[m]     = fmaf(wvv.x, sr, fmaf(-wvv.y, si, ar[m]));         \
                ai[m]     = fmaf(wvv.x, si, fmaf( wvv.y, sr, ai[m]));         \
                ar[m + 1] = fmaf(wvv.z, sr, fmaf(-wvv.w, si, ar[m + 1]));     \
                ai[m + 1] = fmaf(wvv.z, si, fmaf( wvv.w, sr, ai[m + 1]));     \
            }                                                                 \
        }
        DO_Q(0, re.x, im.x)
        DO_Q(1, re.y, im.y)
        DO_Q(2, re.z, im.z)
        DO_Q(3, re.w, im.w)
        #undef DO_Q
    }

    // ---- nontemporal stores (avoid write-allocate fetches) ----
    const long r = row0 + t;
    if (r < batch) {
        f32x4* o4 = (f32x4*)out + r * 16;
        #pragma unroll
        for (int m2 = 0; m2 < 16; ++m2) {
            f32x4 v = { ar[2 * m2], ai[2 * m2], ar[2 * m2 + 1], ai[2 * m2 + 1] };
            __builtin_nontemporal_store(v, o4 + m2);
        }
    }
}

extern "C" void kernel_launch(void* const* d_in, const int* in_sizes, int n_in,
                              void* d_out, int out_size, void* d_ws, size_t ws_size,
                              hipStream_t stream) {
    const float* sre = (const float*)d_in[0];
    const float* sim = (const float*)d_in[1];
    const int batch = in_sizes[0] / CUT;

    build_W<<<1, 64, 0, stream>>>((const float*)d_in[2], (const float*)d_in[3],
                                  (const float*)d_in[4], (const float*)d_in[5],
                                  (const float*)d_in[6], (const float*)d_in[7]);

    const int blocks = (batch + TILE - 1) / TILE;
    apply_W<<<blocks, 256, 0, stream>>>(sre, sim, (float*)d_out, batch);
}

// Round 3
// 526.824 us; speedup vs baseline: 2.2823x; 2.2823x over previous
//
#include <hip/hip_runtime.h>

#define CUT 32

// W2[n][m] = (re, im) of kerr[m] * G[m][n], interleaved. 8 KiB.
__device__ __align__(16) float g_W2[CUT * CUT * 2];

// ---------------------------------------------------------------------------
// Kernel A: build the Gaussian-unitary matrix (with Kerr folded in) in fp64.
// One wave. Lane m (m < 32) owns row m of the current column.
// ---------------------------------------------------------------------------
__global__ __launch_bounds__(64) void build_W(
    const float* __restrict__ gre, const float* __restrict__ gim,
    const float* __restrict__ phi_p, const float* __restrict__ zre,
    const float* __restrict__ zim, const float* __restrict__ kap)
{
    const int lane = threadIdx.x;

    const double gr = (double)gre[0], gi = (double)gim[0];
    const double ph = (double)phi_p[0];
    const double zr = (double)zre[0], zi = (double)zim[0];
    const double kp = (double)kap[0];

    const double r     = sqrt(zr * zr + zi * zi);
    const double delta = atan2(zi, zr);
    const double T     = tanh(r);
    const double sech  = 1.0 / cosh(r);

    const double adp = delta + 2.0 * ph;
    const double edr = cos(adp), edi = sin(adp);   // e^{i(delta+2phi)}

    // g00 = exp(-0.5*(|g|^2 + conj(g)^2 * eidp * T)) * sqrt(sech)
    const double cg2r = gr * gr - gi * gi, cg2i = -2.0 * gr * gi;
    const double wr_  = (cg2r * edr - cg2i * edi) * T;
    const double wi_  = (cg2r * edi + cg2i * edr) * T;
    const double exr  = -0.5 * (gr * gr + gi * gi + wr_);
    const double exi  = -0.5 * wi_;
    const double mag  = exp(exr) * sqrt(sech);
    const double g00r = mag * cos(exi), g00i = mag * sin(exi);

    // A = gamma + conj(gamma)*eidp*T ; B = eidp*T
    const double cgTr = (gr * edr + gi * edi) * T;
    const double cgTi = (gr * edi - gi * edr) * T;
    const double Ar = gr + cgTr, Ai = gi + cgTi;
    const double Br = edr * T,   Bi = edi * T;

    // per-lane sqrt tables (extracted with __shfl during the serial loops)
    const double dl  = (double)lane;
    const double sq  = sqrt(dl);                       // sqrt(lane)
    const double isq = (lane > 0) ? 1.0 / sq : 0.0;    // 1/sqrt(lane)

    // ---- column 0: serial three-term recurrence in m (uniform values) ----
    double cr = (lane == 0) ? g00r : 0.0;
    double ci = (lane == 0) ? g00i : 0.0;
    double g1r = g00r, g1i = g00i, g2r = 0.0, g2i = 0.0;
    for (int m = 1; m < CUT; ++m) {
        const double sm1 = __shfl(sq, m - 1);
        const double ism = __shfl(isq, m);
        double tr = Ar * g1r - Ai * g1i - sm1 * (Br * g2r - Bi * g2i);
        double ti = Ar * g1i + Ai * g1r - sm1 * (Br * g2i + Bi * g2r);
        tr *= ism; ti *= ism;
        if (lane == m) { cr = tr; ci = ti; }
        g2r = g1r; g2i = g1i; g1r = tr; g1i = ti;
    }

    const double Pr = cos(ph) * sech,  Pi = sin(ph) * sech;   // e^{i phi} sech
    const double Qr = cos(delta) * T,  Qi = -sin(delta) * T;  // e^{-i delta} tanh
    const double gbr = gr, gbi = -gi;                         // conj(gamma)

    // Kerr factor for row m = lane: e^{i kappa m^2}
    const double ka = kp * dl * dl;
    const double kr = cos(ka), ki = sin(ka);

    if (lane < CUT) {
        g_W2[(0 * CUT + lane) * 2 + 0] = (float)(kr * cr - ki * ci);
        g_W2[(0 * CUT + lane) * 2 + 1] = (float)(kr * ci + ki * cr);
    }

    // ---- columns n -> n+1: parallel in m, shift via shfl_up ----
    double pr = 0.0, pi = 0.0;
    for (int n = 0; n < CUT - 1; ++n) {
        double upr = __shfl_up(cr, 1);
        double upi = __shfl_up(ci, 1);
        if (lane == 0) { upr = 0.0; upi = 0.0; }
        const double sn   = __shfl(sq, n);
        const double isn1 = __shfl(isq, n + 1);
        // t = sqrt(m)*c[m-1] - conj(gamma)*c[m]
        const double tr = sq * upr - (gbr * cr - gbi * ci);
        const double ti = sq * upi - (gbr * ci + gbi * cr);
        // u = (P*t + Q*sqrt(n)*c_prev) / sqrt(n+1)
        double ur = (Pr * tr - Pi * ti + sn * (Qr * pr - Qi * pi)) * isn1;
        double ui = (Pr * ti + Pi * tr + sn * (Qr * pi + Qi * pr)) * isn1;
        if (lane < CUT) {
            g_W2[((n + 1) * CUT + lane) * 2 + 0] = (float)(kr * ur - ki * ui);
            g_W2[((n + 1) * CUT + lane) * 2 + 1] = (float)(kr * ui + ki * ur);
        }
        pr = cr; pi = ci; cr = ur; ci = ui;
    }
}

// ---------------------------------------------------------------------------
// Kernel B: out[b,m] = sum_n W[m,n] * state[b,n].
// One row per LANE-PAIR. Lane parity p:
//   - loads its contiguous 64 B half-row (n in [16p,16p+16)) as 4 float4 from
//     each of sre/sim -> perfectly coalesced, each HBM line touched once,
//     data held in 32 VGPRs (no LDS staging of state, no spill).
//   - computes only m in [16p,16p+16): 32 fp32 accumulators.
//   - phase 1 consumes its own 16 n-values; phase 2 consumes the partner's
//     via __shfl_xor(.,1) (DPP quad_perm, ~2 VALU/n). Accumulation over n is
//     commutative, so the two lanes walk W at different n-bases; the two
//     distinct LDS addresses per wave are 2-way same-bank (free, m136).
// W broadcast from 8 KB LDS; normal cached stores (L2 merges the 16 B
// strided stores into full lines -- round 0 measured ideal WRITE_SIZE).
// ---------------------------------------------------------------------------
__global__ __launch_bounds__(256, 4) void apply_W(
    const float* __restrict__ sre, const float* __restrict__ sim,
    float* __restrict__ out, int batch)
{
    __shared__ __align__(16) float W[CUT * CUT * 2];
    const int t = threadIdx.x;
    {
        const float4* src = (const float4*)g_W2;
        float4* dst = (float4*)W;
        dst[t]       = src[t];
        dst[t + 256] = src[t + 256];
    }
    __syncthreads();

    const int p = t & 1;
    const long row = (long)blockIdx.x * 128 + (t >> 1);
    if (row >= batch) return;

    // own half-row: n in [16p, 16p+16), contiguous 64 B in each array
    const float4* sre4 = (const float4*)sre + row * 8 + p * 4;
    const float4* sim4 = (const float4*)sim + row * 8 + p * 4;
    const float4 re0 = sre4[0], re1 = sre4[1], re2 = sre4[2], re3 = sre4[3];
    const float4 im0 = sim4[0], im1 = sim4[1], im2 = sim4[2], im3 = sim4[3];

    float ar[16], ai[16];
    #pragma unroll
    for (int m = 0; m < 16; ++m) { ar[m] = 0.f; ai[m] = 0.f; }

    // W float offsets: row n starts at n*64; this lane's m-range at +32p.
    // phase 1: n = 16p + j   -> base = j*64 + p*1056
    // phase 2: n = 16(1-p)+j -> base = j*64 + 1024 - 992p
    const float* W1 = W + p * 1056;
    const float* W2p = W + 1024 - p * 992;

    #define NSTEP(Wn, SR, SI)                                                 \
    {                                                                         \
        const float sr_ = SR, si_ = SI;                                       \
        _Pragma("unroll")                                                     \
        for (int m2 = 0; m2 < 8; ++m2) {                                      \
            const float4 wv = *(const float4*)((Wn) + 4 * m2);                \
            ar[2*m2]   = fmaf(wv.x, sr_, fmaf(-wv.y, si_, ar[2*m2]));         \
            ai[2*m2]   = fmaf(wv.x, si_, fmaf( wv.y, sr_, ai[2*m2]));         \
            ar[2*m2+1] = fmaf(wv.z, sr_, fmaf(-wv.w, si_, ar[2*m2+1]));       \
            ai[2*m2+1] = fmaf(wv.z, si_, fmaf( wv.w, sr_, ai[2*m2+1]));       \
        }                                                                     \
    }

    // ---- phase 1: own 16 n-values ----
    NSTEP(W1 +  0 * 64, re0.x, im0.x)
    NSTEP(W1 +  1 * 64, re0.y, im0.y)
    NSTEP(W1 +  2 * 64, re0.z, im0.z)
    NSTEP(W1 +  3 * 64, re0.w, im0.w)
    NSTEP(W1 +  4 * 64, re1.x, im1.x)
    NSTEP(W1 +  5 * 64, re1.y, im1.y)
    NSTEP(W1 +  6 * 64, re1.z, im1.z)
    NSTEP(W1 +  7 * 64, re1.w, im1.w)
    NSTEP(W1 +  8 * 64, re2.x, im2.x)
    NSTEP(W1 +  9 * 64, re2.y, im2.y)
    NSTEP(W1 + 10 * 64, re2.z, im2.z)
    NSTEP(W1 + 11 * 64, re2.w, im2.w)
    NSTEP(W1 + 12 * 64, re3.x, im3.x)
    NSTEP(W1 + 13 * 64, re3.y, im3.y)
    NSTEP(W1 + 14 * 64, re3.z, im3.z)
    NSTEP(W1 + 15 * 64, re3.w, im3.w)

    // ---- phase 2: partner's 16 n-values via lane^1 exchange ----
    #define NSTEP_X(J, RC, IC) \
        NSTEP(W2p + (J) * 64, __shfl_xor(RC, 1), __shfl_xor(IC, 1))
    NSTEP_X( 0, re0.x, im0.x)
    NSTEP_X( 1, re0.y, im0.y)
    NSTEP_X( 2, re0.z, im0.z)
    NSTEP_X( 3, re0.w, im0.w)
    NSTEP_X( 4, re1.x, im1.x)
    NSTEP_X( 5, re1.y, im1.y)
    NSTEP_X( 6, re1.z, im1.z)
    NSTEP_X( 7, re1.w, im1.w)
    NSTEP_X( 8, re2.x, im2.x)
    NSTEP_X( 9, re2.y, im2.y)
    NSTEP_X(10, re2.z, im2.z)
    NSTEP_X(11, re2.w, im2.w)
    NSTEP_X(12, re3.x, im3.x)
    NSTEP_X(13, re3.y, im3.y)
    NSTEP_X(14, re3.z, im3.z)
    NSTEP_X(15, re3.w, im3.w)
    #undef NSTEP_X
    #undef NSTEP

    // ---- stores: lane covers m in [16p,16p+16) = contiguous 128 B ----
    float4* o4 = (float4*)out + row * 16 + p * 8;
    #pragma unroll
    for (int m2 = 0; m2 < 8; ++m2) {
        o4[m2] = make_float4(ar[2 * m2], ai[2 * m2],
                             ar[2 * m2 + 1], ai[2 * m2 + 1]);
    }
}

extern "C" void kernel_launch(void* const* d_in, const int* in_sizes, int n_in,
                              void* d_out, int out_size, void* d_ws, size_t ws_size,
                              hipStream_t stream) {
    const float* sre = (const float*)d_in[0];
    const float* sim = (const float*)d_in[1];
    const int batch = in_sizes[0] / CUT;

    build_W<<<1, 64, 0, stream>>>((const float*)d_in[2], (const float*)d_in[3],
                                  (const float*)d_in[4], (const float*)d_in[5],
                                  (const float*)d_in[6], (const float*)d_in[7]);

    const int blocks = (batch + 127) / 128;
    apply_W<<<blocks, 256, 0, stream>>>(sre, sim, (float*)d_out, batch);
}

// Round 4
// 469.013 us; speedup vs baseline: 2.5636x; 1.1233x over previous
//
#include <hip/hip_runtime.h>

#define CUT 32

// Real-embedded, transposed Gaussian+Kerr matrix:
// g_Bt[mm][kk], mm = 2m+c (c: 0=re,1=im of output), kk = n + 32d (d: 0=sre,1=sim).
// out2[b][mm] = sum_kk A2[b][kk] * g_Bt[mm][kk], A2[b] = [sre_row | sim_row].
// 64x64 f32 = 16 KiB.
__device__ __align__(16) float g_Bt[64 * 64];

// ---------------------------------------------------------------------------
// Kernel A: build the Gaussian-unitary matrix (with Kerr folded in) in fp64.
// One wave. Lane m (m < 32) owns row m of the current column. Writes the
// real-embedded matrix g_Bt directly:
//   g_Bt[2m][n]      =  Wr     g_Bt[2m][n+32]   = -Wi
//   g_Bt[2m+1][n]    =  Wi     g_Bt[2m+1][n+32] =  Wr
// where Wr + i*Wi = kerr[m] * G[m][n].
// ---------------------------------------------------------------------------
__global__ __launch_bounds__(64) void build_W(
    const float* __restrict__ gre, const float* __restrict__ gim,
    const float* __restrict__ phi_p, const float* __restrict__ zre,
    const float* __restrict__ zim, const float* __restrict__ kap)
{
    const int lane = threadIdx.x;

    const double gr = (double)gre[0], gi = (double)gim[0];
    const double ph = (double)phi_p[0];
    const double zr = (double)zre[0], zi = (double)zim[0];
    const double kp = (double)kap[0];

    const double r     = sqrt(zr * zr + zi * zi);
    const double delta = atan2(zi, zr);
    const double T     = tanh(r);
    const double sech  = 1.0 / cosh(r);

    const double adp = delta + 2.0 * ph;
    const double edr = cos(adp), edi = sin(adp);   // e^{i(delta+2phi)}

    // g00 = exp(-0.5*(|g|^2 + conj(g)^2 * eidp * T)) * sqrt(sech)
    const double cg2r = gr * gr - gi * gi, cg2i = -2.0 * gr * gi;
    const double wr_  = (cg2r * edr - cg2i * edi) * T;
    const double wi_  = (cg2r * edi + cg2i * edr) * T;
    const double exr  = -0.5 * (gr * gr + gi * gi + wr_);
    const double exi  = -0.5 * wi_;
    const double mag  = exp(exr) * sqrt(sech);
    const double g00r = mag * cos(exi), g00i = mag * sin(exi);

    // A = gamma + conj(gamma)*eidp*T ; B = eidp*T
    const double cgTr = (gr * edr + gi * edi) * T;
    const double cgTi = (gr * edi - gi * edr) * T;
    const double Ar = gr + cgTr, Ai = gi + cgTi;
    const double Br = edr * T,   Bi = edi * T;

    const double dl  = (double)lane;
    const double sq  = sqrt(dl);                       // sqrt(lane)
    const double isq = (lane > 0) ? 1.0 / sq : 0.0;    // 1/sqrt(lane)

    // ---- column 0: serial three-term recurrence in m (uniform values) ----
    double cr = (lane == 0) ? g00r : 0.0;
    double ci = (lane == 0) ? g00i : 0.0;
    double g1r = g00r, g1i = g00i, g2r = 0.0, g2i = 0.0;
    for (int m = 1; m < CUT; ++m) {
        const double sm1 = __shfl(sq, m - 1);
        const double ism = __shfl(isq, m);
        double tr = Ar * g1r - Ai * g1i - sm1 * (Br * g2r - Bi * g2i);
        double ti = Ar * g1i + Ai * g1r - sm1 * (Br * g2i + Bi * g2r);
        tr *= ism; ti *= ism;
        if (lane == m) { cr = tr; ci = ti; }
        g2r = g1r; g2i = g1i; g1r = tr; g1i = ti;
    }

    const double Pr = cos(ph) * sech,  Pi = sin(ph) * sech;   // e^{i phi} sech
    const double Qr = cos(delta) * T,  Qi = -sin(delta) * T;  // e^{-i delta} tanh
    const double gbr = gr, gbi = -gi;                         // conj(gamma)

    // Kerr factor for row m = lane: e^{i kappa m^2}
    const double ka = kp * dl * dl;
    const double kr = cos(ka), ki = sin(ka);

    if (lane < CUT) {
        const float Wr = (float)(kr * cr - ki * ci);
        const float Wi = (float)(kr * ci + ki * cr);
        float* b0 = &g_Bt[(2 * lane) * 64];
        float* b1 = &g_Bt[(2 * lane + 1) * 64];
        b0[0]      =  Wr;  b0[0 + 32] = -Wi;
        b1[0]      =  Wi;  b1[0 + 32] =  Wr;
    }

    // ---- columns n -> n+1: parallel in m, shift via shfl_up ----
    double pr = 0.0, pi = 0.0;
    for (int n = 0; n < CUT - 1; ++n) {
        double upr = __shfl_up(cr, 1);
        double upi = __shfl_up(ci, 1);
        if (lane == 0) { upr = 0.0; upi = 0.0; }
        const double sn   = __shfl(sq, n);
        const double isn1 = __shfl(isq, n + 1);
        const double tr = sq * upr - (gbr * cr - gbi * ci);
        const double ti = sq * upi - (gbr * ci + gbi * cr);
        double ur = (Pr * tr - Pi * ti + sn * (Qr * pr - Qi * pi)) * isn1;
        double ui = (Pr * ti + Pi * tr + sn * (Qr * pi + Qi * pr)) * isn1;
        if (lane < CUT) {
            const float Wr = (float)(kr * ur - ki * ui);
            const float Wi = (float)(kr * ui + ki * ur);
            float* b0 = &g_Bt[(2 * lane) * 64];
            float* b1 = &g_Bt[(2 * lane + 1) * 64];
            b0[n + 1]      =  Wr;  b0[n + 1 + 32] = -Wi;
            b1[n + 1]      =  Wi;  b1[n + 1 + 32] =  Wr;
        }
        pr = cr; pi = ci; cr = ur; ci = ui;
    }
}

// ---------------------------------------------------------------------------
// Kernel B: MFMA GEMM  out2[1M x 64] = A2[1M x 64] * B2[64 x 64].
// Split-bf16 (hi+lo truncation, 3-product) for ~2^-16 relative accuracy.
// W fragments (B-operand) live permanently in wave registers -> no LDS and no
// per-FMA W reads. Per 16-row tile: 4 coalesced dwordx4 loads (permutation
// within a contiguous 4 KB block, single-touch), ~100 VALU ops of splitting,
// 24 mfma_f32_16x16x32_bf16, 16 dword stores (L2 merges to full lines).
// Fragment maps (m89-verified C/D; canonical A/B):
//   A: lane l -> row l&15,  k = 8*(l>>4)+j
//   B: lane l -> col l&15,  k = 8*(l>>4)+j
//   D: lane l, reg r -> row (l>>4)*4+r, col l&15
// ---------------------------------------------------------------------------
typedef __attribute__((ext_vector_type(8))) short bf16x8;
typedef __attribute__((ext_vector_type(4))) float f32x4;

__device__ __forceinline__ void split8(const float4 a, const float4 b,
                                       bf16x8& hi, bf16x8& lo) {
    const float v[8] = {a.x, a.y, a.z, a.w, b.x, b.y, b.z, b.w};
    #pragma unroll
    for (int j = 0; j < 8; ++j) {
        const unsigned u  = __float_as_uint(v[j]);
        const unsigned h  = u >> 16;                       // truncate to bf16
        const float    hf = __uint_as_float(h << 16);
        const float    l  = v[j] - hf;                     // exact residual
        const unsigned lu = __float_as_uint(l) >> 16;      // truncate residual
        hi[j] = (short)h;
        lo[j] = (short)lu;
    }
}

__global__ __launch_bounds__(256, 3) void apply_W(
    const float* __restrict__ sre, const float* __restrict__ sim,
    float* __restrict__ out, int batch)
{
    const int t    = threadIdx.x;
    const int lane = t & 63;
    const int wv   = t >> 6;
    const int l15  = lane & 15;
    const int l4   = lane >> 4;

    // ---- per-wave W fragments (16 KiB g_Bt, L2-hot after first wave) ----
    bf16x8 Bh[2][4], Bl[2][4];
    #pragma unroll
    for (int kt = 0; kt < 2; ++kt) {
        #pragma unroll
        for (int nt = 0; nt < 4; ++nt) {
            const float4* p =
                (const float4*)&g_Bt[(16 * nt + l15) * 64 + 32 * kt + 8 * l4];
            split8(p[0], p[1], Bh[kt][nt], Bl[kt][nt]);
        }
    }

    const long nwaves = (long)gridDim.x * 4;
    const long wgid   = (long)blockIdx.x * 4 + wv;
    const long ntiles = ((long)batch + 15) >> 4;

    for (long tile = wgid; tile < ntiles; tile += nwaves) {
        const long b0 = tile << 4;

        long rowA = b0 + l15;
        if (rowA > (long)batch - 1) rowA = (long)batch - 1;  // tail clamp
        const float4* pre = (const float4*)(sre + rowA * 32 + 8 * l4);
        const float4* pim = (const float4*)(sim + rowA * 32 + 8 * l4);
        const float4 a0 = pre[0], a1 = pre[1];
        const float4 c0 = pim[0], c1 = pim[1];

        bf16x8 Ah0, Al0, Ah1, Al1;
        split8(a0, a1, Ah0, Al0);   // kt=0: sre half of K
        split8(c0, c1, Ah1, Al1);   // kt=1: sim half of K

        f32x4 acc[4];
        #pragma unroll
        for (int nt = 0; nt < 4; ++nt) {
            f32x4 c = {0.f, 0.f, 0.f, 0.f};
            c = __builtin_amdgcn_mfma_f32_16x16x32_bf16(Ah0, Bh[0][nt], c, 0, 0, 0);
            c = __builtin_amdgcn_mfma_f32_16x16x32_bf16(Ah1, Bh[1][nt], c, 0, 0, 0);
            c = __builtin_amdgcn_mfma_f32_16x16x32_bf16(Ah0, Bl[0][nt], c, 0, 0, 0);
            c = __builtin_amdgcn_mfma_f32_16x16x32_bf16(Ah1, Bl[1][nt], c, 0, 0, 0);
            c = __builtin_amdgcn_mfma_f32_16x16x32_bf16(Al0, Bh[0][nt], c, 0, 0, 0);
            c = __builtin_amdgcn_mfma_f32_16x16x32_bf16(Al1, Bh[1][nt], c, 0, 0, 0);
            acc[nt] = c;
        }

        // ---- store: lane covers rows l4*4..+4 at col l15 (+16 per nt) ----
        const long orow = b0 + l4 * 4;
        float* po = out + orow * 64 + l15;
        if (b0 + 16 <= (long)batch) {
            #pragma unroll
            for (int rg = 0; rg < 4; ++rg) {
                #pragma unroll
                for (int nt = 0; nt < 4; ++nt) {
                    po[rg * 64 + nt * 16] = acc[nt][rg];
                }
            }
        } else {
            #pragma unroll
            for (int rg = 0; rg < 4; ++rg) {
                if (orow + rg < (long)batch) {
                    #pragma unroll
                    for (int nt = 0; nt < 4; ++nt) {
                        po[rg * 64 + nt * 16] = acc[nt][rg];
                    }
                }
            }
        }
    }
}

extern "C" void kernel_launch(void* const* d_in, const int* in_sizes, int n_in,
                              void* d_out, int out_size, void* d_ws, size_t ws_size,
                              hipStream_t stream) {
    const float* sre = (const float*)d_in[0];
    const float* sim = (const float*)d_in[1];
    const int batch = in_sizes[0] / CUT;

    build_W<<<1, 64, 0, stream>>>((const float*)d_in[2], (const float*)d_in[3],
                                  (const float*)d_in[4], (const float*)d_in[5],
                                  (const float*)d_in[6], (const float*)d_in[7]);

    const long ntiles = ((long)batch + 15) / 16;
    long blocks = (ntiles + 3) / 4;          // 4 waves per block
    if (blocks > 2048) blocks = 2048;        // ~8 tiles per wave at full batch
    if (blocks < 1) blocks = 1;
    apply_W<<<(int)blocks, 256, 0, stream>>>(sre, sim, (float*)d_out, batch);
}